// Round 4
// baseline (125.914 us; speedup 1.0000x reference)
//
#include <hip/hip_runtime.h>
#include <hip/hip_cooperative_groups.h>

namespace cg = cooperative_groups;

// Problem constants (match reference)
#define B_ 16
#define N_ 8192
#define U_ 64        // INPUT_DIM
#define W_ 128       // LATENT_DIM
#define BLOCKS_PER_B 32
#define ROWS_PER_BLOCK (N_ / BLOCKS_PER_B)   // 256
#define GRID_ (B_ * BLOCKS_PER_B)            // 512 blocks = 2/CU, coop-safe

// ws layout: [GRID_][256] block-partial sums.
//   slot tid encodes (u = tid>>2, j = tid&3); j==0 -> sum feat_u, j=1..3 -> sum feat_u*nhat_{j-1}
// out layout: [B,512]: o<128 scalar path, 128+3w+k vector path

// ---------------- shared phase-1 body ----------------
__device__ __forceinline__ void reduce_phase(
    const float* __restrict__ feat, const float* __restrict__ pos,
    float* __restrict__ ws, const int blk, const int tid)
{
    const int b     = blk / BLOCKS_PER_B;
    const int chunk = blk % BLOCKS_PER_B;
    const int row0  = chunk * ROWS_PER_BLOCK;
    const int grp   = tid & 15;                // feature group: features 4*grp..4*grp+3
    const int rsub  = tid >> 4;                // 0..15: row within a 16-row group

    float accS[4] = {0.f, 0.f, 0.f, 0.f};
    float accM[4][3] = {{0.f,0.f,0.f},{0.f,0.f,0.f},{0.f,0.f,0.f},{0.f,0.f,0.f}};

    const float4* fbase = (const float4*)(feat + (size_t)b * N_ * U_);
    const float*  pbase = pos + (size_t)b * N_ * 3;

    #pragma unroll 8
    for (int it = 0; it < ROWS_PER_BLOCK; it += 16) {
        const int n = row0 + it + rsub;
        const float4 f = fbase[(size_t)n * 16 + grp];   // 16 B/lane, coalesced
        const float px = pbase[n * 3 + 0];
        const float py = pbase[n * 3 + 1];
        const float pz = pbase[n * 3 + 2];
        const float inv = rsqrtf(px * px + py * py + pz * pz);
        const float nx = px * inv, ny = py * inv, nz = pz * inv;

        accS[0] += f.x; accS[1] += f.y; accS[2] += f.z; accS[3] += f.w;
        accM[0][0] += f.x * nx; accM[0][1] += f.x * ny; accM[0][2] += f.x * nz;
        accM[1][0] += f.y * nx; accM[1][1] += f.y * ny; accM[1][2] += f.y * nz;
        accM[2][0] += f.z * nx; accM[2][1] += f.z * ny; accM[2][2] += f.z * nz;
        accM[3][0] += f.w * nx; accM[3][1] += f.w * ny; accM[3][2] += f.w * nz;
    }

    // Block-level combine via LDS (pad 17 breaks the stride-16 bank pattern).
    __shared__ float lds[256][17];
    lds[tid][0] = accS[0]; lds[tid][1] = accS[1];
    lds[tid][2] = accS[2]; lds[tid][3] = accS[3];
    #pragma unroll
    for (int i = 0; i < 4; ++i) {
        lds[tid][4 + i * 3 + 0] = accM[i][0];
        lds[tid][4 + i * 3 + 1] = accM[i][1];
        lds[tid][4 + i * 3 + 2] = accM[i][2];
    }
    __syncthreads();

    const int u    = tid >> 2;     // 0..63
    const int j    = tid & 3;      // 0 = S, 1..3 = M[k]
    const int ug   = u >> 2;       // writer feature-group
    const int sub  = u & 3;        // which of writer's 4 features
    const int slot = (j == 0) ? sub : (4 + sub * 3 + (j - 1));
    float s = 0.f;
    #pragma unroll
    for (int src = 0; src < 16; ++src) {
        const int t = (src & 3) * 64 + (src >> 2) * 16 + ug;
        s += lds[t][slot];
    }
    ws[(size_t)blk * 256 + tid] = s;   // coalesced 1 KiB store
}

// ---------------- fused cooperative kernel ----------------
__global__ __launch_bounds__(256) void so3_coop_kernel(
    const float* __restrict__ feat, const float* __restrict__ pos,
    const float* __restrict__ W0, const float* __restrict__ W1,
    float* __restrict__ out, float* __restrict__ ws)
{
    const int blk = blockIdx.x;
    const int tid = threadIdx.x;

    reduce_phase(feat, pos, ws, blk, tid);

    __threadfence();            // device-scope release: push partials past XCD L2
    cg::this_grid().sync();
    __threadfence();            // acquire side

    if (blk >= B_) return;
    const int bb = blk;

    __shared__ float sm[256];
    {
        float s = 0.f;
        const float* base = ws + (size_t)bb * BLOCKS_PER_B * 256;
        #pragma unroll
        for (int c = 0; c < BLOCKS_PER_B; ++c) s += base[(size_t)c * 256 + tid];
        sm[tid] = s;
    }
    __syncthreads();

    const float scaleS = 0.125f / (float)N_;
    const float scaleV = 0.125f * 1.7320508075688772f / (float)N_;

    #pragma unroll
    for (int half = 0; half < 2; ++half) {
        const int o = tid + half * 256;
        float acc = 0.f;
        if (o < 128) {
            #pragma unroll
            for (int u = 0; u < 64; ++u) acc += sm[u * 4] * W0[u * 128 + o];
            out[bb * 512 + o] = acc * scaleS;
        } else {
            const int idx = o - 128;
            const int w = idx / 3;
            const int k = idx - 3 * w;
            #pragma unroll
            for (int u = 0; u < 64; ++u) acc += sm[u * 4 + 1 + k] * W1[u * 128 + w];
            out[bb * 512 + 128 + idx] = acc * scaleV;
        }
    }
}

// ---------------- fallback: 2-kernel deterministic path ----------------
__global__ __launch_bounds__(256) void so3_reduce_kernel(
    const float* __restrict__ feat, const float* __restrict__ pos,
    float* __restrict__ ws)
{
    reduce_phase(feat, pos, ws, blockIdx.x, threadIdx.x);
}

__global__ __launch_bounds__(512) void so3_finalize_kernel(
    const float* __restrict__ ws, const float* __restrict__ W0,
    const float* __restrict__ W1, float* __restrict__ out)
{
    const int b   = blockIdx.x;
    const int tid = threadIdx.x;    // 0..511

    __shared__ float sm2[512];
    __shared__ float sm[256];
    {
        const int slot = tid & 255;
        const int half = tid >> 8;
        const float* base = ws + ((size_t)b * BLOCKS_PER_B + half * 16) * 256;
        float s = 0.f;
        #pragma unroll
        for (int c = 0; c < 16; ++c) s += base[(size_t)c * 256 + slot];
        sm2[tid] = s;
    }
    __syncthreads();
    if (tid < 256) sm[tid] = sm2[tid] + sm2[tid + 256];
    __syncthreads();

    const float scaleS = 0.125f / (float)N_;
    const float scaleV = 0.125f * 1.7320508075688772f / (float)N_;

    const int o = tid;              // one output per thread
    float acc = 0.f;
    if (o < 128) {
        #pragma unroll
        for (int u = 0; u < 64; ++u) acc += sm[u * 4] * W0[u * 128 + o];
        out[b * 512 + o] = acc * scaleS;
    } else {
        const int idx = o - 128;
        const int w = idx / 3;
        const int k = idx - 3 * w;
        #pragma unroll
        for (int u = 0; u < 64; ++u) acc += sm[u * 4 + 1 + k] * W1[u * 128 + w];
        out[b * 512 + 128 + idx] = acc * scaleV;
    }
}

extern "C" void kernel_launch(void* const* d_in, const int* in_sizes, int n_in,
                              void* d_out, int out_size, void* d_ws, size_t ws_size,
                              hipStream_t stream) {
    const float* feat = (const float*)d_in[0];
    const float* pos  = (const float*)d_in[1];
    const float* W0   = (const float*)d_in[2];
    const float* W1   = (const float*)d_in[3];
    float* out = (float*)d_out;
    float* ws  = (float*)d_ws;   // needs GRID_*256*4 = 512 KiB scratch

    void* args[] = { (void*)&feat, (void*)&pos, (void*)&W0, (void*)&W1,
                     (void*)&out, (void*)&ws };
    hipError_t e = hipLaunchCooperativeKernel((const void*)so3_coop_kernel,
                                              dim3(GRID_), dim3(256),
                                              args, 0, stream);
    if (e != hipSuccess) {
        // Cooperative enqueue rejected (occupancy / capture) -> deterministic
        // 2-kernel path on the same stream.
        so3_reduce_kernel<<<GRID_, 256, 0, stream>>>(feat, pos, ws);
        so3_finalize_kernel<<<B_, 512, 0, stream>>>(ws, W0, W1, out);
    }
}

// Round 5
// 14.195 us; speedup vs baseline: 8.8703x; 8.8703x over previous
//
#include <hip/hip_runtime.h>

// Problem constants (match reference)
#define B_ 16
#define N_ 8192
#define U_ 64        // INPUT_DIM
#define W_ 128       // LATENT_DIM
#define BLOCKS_PER_B 64
#define ROWS_PER_BLOCK (N_ / BLOCKS_PER_B)   // 128

// ws layout: [B*BLOCKS_PER_B][256] block-partial sums.
//   slot = u*4 + j; j==0 -> sum feat_u, j=1..3 -> sum feat_u * nhat_{j-1}
// out layout: [B,512]: o<128 scalar path, 128+3w+k vector path

__global__ __launch_bounds__(256) void so3_reduce_kernel(
    const float* __restrict__ feat,   // [B,N,64]
    const float* __restrict__ pos,    // [B,N,3]
    float* __restrict__ ws)           // [B*64][256] partials (written, not accumulated)
{
    const int blk   = blockIdx.x;              // 0 .. B*BLOCKS_PER_B-1
    const int b     = blk / BLOCKS_PER_B;
    const int chunk = blk % BLOCKS_PER_B;
    const int row0  = chunk * ROWS_PER_BLOCK;
    const int tid   = threadIdx.x;             // 0..255 (4 waves)
    const int grp   = tid & 15;                // feature group: features 4*grp .. 4*grp+3
    const int rsub  = tid >> 4;                // 0..15: row within a 16-row group

    float accS[4] = {0.f, 0.f, 0.f, 0.f};
    float accM[4][3] = {{0.f,0.f,0.f},{0.f,0.f,0.f},{0.f,0.f,0.f},{0.f,0.f,0.f}};

    const float4* fbase = (const float4*)(feat + (size_t)b * N_ * U_);
    const float*  pbase = pos + (size_t)b * N_ * 3;

    #pragma unroll
    for (int it = 0; it < ROWS_PER_BLOCK; it += 16) {
        const int n = row0 + it + rsub;
        const float4 f = fbase[(size_t)n * 16 + grp];   // 16 B/lane; wave = 1 KiB contiguous
        const float px = pbase[n * 3 + 0];
        const float py = pbase[n * 3 + 1];
        const float pz = pbase[n * 3 + 2];
        const float inv = rsqrtf(px * px + py * py + pz * pz);
        const float nx = px * inv, ny = py * inv, nz = pz * inv;

        accS[0] += f.x; accS[1] += f.y; accS[2] += f.z; accS[3] += f.w;
        accM[0][0] += f.x * nx; accM[0][1] += f.x * ny; accM[0][2] += f.x * nz;
        accM[1][0] += f.y * nx; accM[1][1] += f.y * ny; accM[1][2] += f.y * nz;
        accM[2][0] += f.z * nx; accM[2][1] += f.z * ny; accM[2][2] += f.z * nz;
        accM[3][0] += f.w * nx; accM[3][1] += f.w * ny; accM[3][2] += f.w * nz;
    }

    // Block-level combine via LDS (pad 17 breaks the stride-16 bank pattern).
    __shared__ float lds[256][17];
    lds[tid][0] = accS[0]; lds[tid][1] = accS[1];
    lds[tid][2] = accS[2]; lds[tid][3] = accS[3];
    #pragma unroll
    for (int i = 0; i < 4; ++i) {
        lds[tid][4 + i * 3 + 0] = accM[i][0];
        lds[tid][4 + i * 3 + 1] = accM[i][1];
        lds[tid][4 + i * 3 + 2] = accM[i][2];
    }
    __syncthreads();

    const int u    = tid >> 2;     // 0..63
    const int j    = tid & 3;      // 0 = S, 1..3 = M[k]
    const int ug   = u >> 2;       // writer feature-group
    const int sub  = u & 3;        // which of writer's 4 features
    const int slot = (j == 0) ? sub : (4 + sub * 3 + (j - 1));
    float s = 0.f;
    #pragma unroll
    for (int src = 0; src < 16; ++src) {
        const int t = (src & 3) * 64 + (src >> 2) * 16 + ug;  // wave*64 + row-in-wave*16 + ug
        s += lds[t][slot];
    }
    ws[(size_t)blk * 256 + tid] = s;   // coalesced 1 KiB store
}

__global__ __launch_bounds__(512) void so3_finalize_kernel(
    const float* __restrict__ ws,   // [B*64][256] partials
    const float* __restrict__ W0,   // [64,128]
    const float* __restrict__ W1,   // [64,128]
    float* __restrict__ out)        // [B,512]
{
    const int b   = blockIdx.x;
    const int tid = threadIdx.x;    // 0..511

    // Phase 1: cross-block combine, float4-wide. Slot group of 4 = one u
    // (slot = u*4 + j), so thread (cgrp, u) sums float4 over 8 chunks.
    const int u    = tid & 63;      // float4 index within a chunk row
    const int cgrp = tid >> 6;      // 0..7: which chunk group

    __shared__ float4 smf4[8][64];  // 8 KiB
    __shared__ float  sm[256];

    {
        const float4* base = (const float4*)(ws + (size_t)b * BLOCKS_PER_B * 256);
        float4 a = {0.f, 0.f, 0.f, 0.f};
        #pragma unroll
        for (int c = 0; c < 8; ++c) {
            // chunk index = cgrp*8 + c; each chunk row = 64 float4s.
            const float4 v = base[(size_t)(cgrp * 8 + c) * 64 + u];
            a.x += v.x; a.y += v.y; a.z += v.z; a.w += v.w;
        }
        smf4[cgrp][u] = a;
    }
    __syncthreads();

    if (tid < 64) {
        float4 t = smf4[0][tid];
        #pragma unroll
        for (int g = 1; g < 8; ++g) {
            const float4 v = smf4[g][tid];
            t.x += v.x; t.y += v.y; t.z += v.z; t.w += v.w;
        }
        ((float4*)sm)[tid] = t;     // sm[u*4 + j]
    }
    __syncthreads();

    // Phase 2: tiny matmul, one output element per thread.
    const float scaleS = 0.125f / (float)N_;                       // PATH_COEFF / N
    const float scaleV = 0.125f * 1.7320508075688772f / (float)N_; // PATH_COEFF*sqrt(3)/N

    const int o = tid;
    float acc = 0.f;
    if (o < 128) {
        #pragma unroll
        for (int uu = 0; uu < 64; ++uu) acc += sm[uu * 4] * W0[uu * 128 + o];
        out[b * 512 + o] = acc * scaleS;
    } else {
        const int idx = o - 128;       // 0..383
        const int w = idx / 3;
        const int k = idx - 3 * w;
        #pragma unroll
        for (int uu = 0; uu < 64; ++uu) acc += sm[uu * 4 + 1 + k] * W1[uu * 128 + w];
        out[b * 512 + 128 + idx] = acc * scaleV;
    }
}

extern "C" void kernel_launch(void* const* d_in, const int* in_sizes, int n_in,
                              void* d_out, int out_size, void* d_ws, size_t ws_size,
                              hipStream_t stream) {
    const float* feat = (const float*)d_in[0];
    const float* pos  = (const float*)d_in[1];
    const float* W0   = (const float*)d_in[2];
    const float* W1   = (const float*)d_in[3];
    float* out = (float*)d_out;
    float* ws  = (float*)d_ws;   // needs B*64*256*4 = 1 MiB scratch

    so3_reduce_kernel<<<B_ * BLOCKS_PER_B, 256, 0, stream>>>(feat, pos, ws);
    so3_finalize_kernel<<<B_, 512, 0, stream>>>(ws, W0, W1, out);
}